// Round 20
// baseline (210.041 us; speedup 1.0000x reference)
//
#include <hip/hip_runtime.h>
#include <hip/hip_bf16.h>
#include <cstdint>
#include <cstddef>

#define BT    16384   // B*T
#define DIN   4096
#define DOUT  4096
#define RR    64
#define TSEQ  2048
#define NADP  8

typedef float  f32x4  __attribute__((ext_vector_type(4)));
typedef __bf16 bf16x8 __attribute__((ext_vector_type(8)));

static __device__ __forceinline__ unsigned short bf16_bits(float f) {
    return __builtin_bit_cast(unsigned short, (__bf16)f);
}

// inter2 swizzled layout: [mblk(1024)][rb(8)][mrow(16)][j(8)]
static __device__ __forceinline__ size_t i2_idx(int mblk, int rb, int mrow, int j) {
    return ((((size_t)mblk * 8 + rb) * 16 + mrow) * 8 + j);
}

static __device__ __forceinline__ bf16x8 cvt8(float4 a, float4 b) {
    bf16x8 v;
    v[0] = (__bf16)a.x; v[1] = (__bf16)a.y; v[2] = (__bf16)a.z; v[3] = (__bf16)a.w;
    v[4] = (__bf16)b.x; v[5] = (__bf16)b.y; v[6] = (__bf16)b.z; v[7] = (__bf16)b.w;
    return v;
}

// ---------------------------------------------------------------------------
// k_prep_a: At2[a][kq][r][j] = bf16(A[a][kq*8+j][r]).  (R8+ verbatim)
// ---------------------------------------------------------------------------
__global__ __launch_bounds__(256) void k_prep_a(
    const float* __restrict__ A, __bf16* __restrict__ At2)
{
    const int gtid = blockIdx.x * 256 + threadIdx.x;
    const int r  = gtid & 63;
    const int kb = (gtid >> 6) & (DIN / 8 - 1);
    const int a  = gtid >> 15;
    const float* __restrict__ src = A + (size_t)a * DIN * RR + (size_t)kb * 8 * RR + r;
    unsigned int u[4];
    #pragma unroll
    for (int p = 0; p < 4; ++p) {
        unsigned int lo = bf16_bits(src[(2 * p + 0) * RR]);
        unsigned int hi = bf16_bits(src[(2 * p + 1) * RR]);
        u[p] = lo | (hi << 16);
    }
    *(uint4*)&At2[(size_t)gtid * 8] = make_uint4(u[0], u[1], u[2], u[3]);
}

// ---------------------------------------------------------------------------
// k_prep_b: Bp[a][rb][o][j] = bf16(B[a][rb*8+j][o]).  (R8+ verbatim)
// ---------------------------------------------------------------------------
__global__ __launch_bounds__(256) void k_prep_b(
    const float* __restrict__ Bw, __bf16* __restrict__ Bp)
{
    const int gtid = blockIdx.x * 256 + threadIdx.x;
    const int o  = gtid & (DOUT - 1);
    const int rb = (gtid >> 12) & 7;
    const int a  = gtid >> 15;
    const float* __restrict__ src = Bw + (size_t)a * RR * DOUT + (size_t)rb * 8 * DOUT + o;
    unsigned int u[4];
    #pragma unroll
    for (int p = 0; p < 4; ++p) {
        unsigned int lo = bf16_bits(src[(2 * p + 0) * DOUT]);
        unsigned int hi = bf16_bits(src[(2 * p + 1) * DOUT]);
        u[p] = lo | (hi << 16);
    }
    *(uint4*)&Bp[(size_t)gtid * 8] = make_uint4(u[0], u[1], u[2], u[3]);
}

// ---------------------------------------------------------------------------
// k_xa: inter2 <- bf16( x @ A[a] ).  R13 structure (best measured) with
// BK 64 -> 128: HALF the barriers/vmcnt-drains (32 tiles instead of 64).
// 512 blocks (32 m-rows) x 4 waves, 2 blocks/CU. LDS [2][32][128] bf16
// (16 KB dbuf). Per thread per tile: 4 float4 loads (2 octets) + 2 bf16x8
// ds_writes; octet slot XOR-swizzled with (row&7) on BOTH write-src and
// read (bit 3 untouched -> bijective per 8-slot half). Wave w: r-tile
// [w*16,+16) x 32 rows (2 m-frag chains). Store convention = R13-proven.
// ---------------------------------------------------------------------------
__global__ __launch_bounds__(256, 2) void k_xa(
    const float* __restrict__ x, const int* __restrict__ idx,
    const __bf16* __restrict__ At2, __bf16* __restrict__ inter2)
{
    __shared__ __bf16 xs[2][32][128];   // 16 KB, double-buffered bf16 x-tile

    const int tid  = threadIdx.x;
    const int m0   = blockIdx.x * 32;
    const int a    = idx[m0 / TSEQ];
    const int w    = tid >> 6, lane = tid & 63;
    const int mr   = lane & 15, kg = lane >> 4;
    const int rcol = w * 16 + mr;

    // staging: thread -> (row srow, octet slots sj and sj+8); source octet
    // pre-swizzled by row (low-3-bit XOR; +8 slot keeps bit 3).
    const int srow = tid >> 3;                 // 0..31
    const int sj   = tid & 7;                  // 0..7
    const int sswz = sj ^ (srow & 7);          // source octet for slot sj
    const float* __restrict__ xsrc = x + (size_t)(m0 + srow) * DIN + sswz * 8;
    // second octet: slot sj+8 <- source octet sswz+8 = +64 floats
    __bf16* const d0a = &xs[0][srow][sj * 8];
    __bf16* const d0b = &xs[0][srow][(sj + 8) * 8];
    __bf16* const d1a = &xs[1][srow][sj * 8];
    __bf16* const d1b = &xs[1][srow][(sj + 8) * 8];

    const __bf16* __restrict__ Aw = At2 + (size_t)a * RR * DIN;

    f32x4 z = {0.f, 0.f, 0.f, 0.f};
    f32x4 acc0 = z, acc1 = z;                  // m-frag 0 (rows 0-15), 1 (16-31)

    float4 eA0, eA1, eB0, eB1;                 // even-buffer staging regs
    float4 oA0, oA1, oB0, oB1;                 // odd-buffer staging regs

    // prologue: load tile0 -> e, tile1 -> o; write tile0 to buf0; barrier
    eA0 = *(const float4*)(xsrc + 0 * 128);
    eA1 = *(const float4*)(xsrc + 0 * 128 + 4);
    eB0 = *(const float4*)(xsrc + 0 * 128 + 64);
    eB1 = *(const float4*)(xsrc + 0 * 128 + 68);
    oA0 = *(const float4*)(xsrc + 1 * 128);
    oA1 = *(const float4*)(xsrc + 1 * 128 + 4);
    oB0 = *(const float4*)(xsrc + 1 * 128 + 64);
    oB1 = *(const float4*)(xsrc + 1 * 128 + 68);
    *(bf16x8*)d0a = cvt8(eA0, eA1);
    *(bf16x8*)d0b = cvt8(eB0, eB1);
    __syncthreads();

#define COMPUTE(B, T)                                                              \
    {                                                                              \
        _Pragma("unroll")                                                          \
        for (int kstep = 0; kstep < 4; ++kstep) {                                  \
            const int kq = kstep * 4 + kg;                       /* 0..15 */       \
            bf16x8 bfw = *(const bf16x8*)&Aw[(((size_t)(T) * 16 + kq) * 64 + rcol) * 8]; \
            bf16x8 af0 = *(const bf16x8*)&xs[B][mr]     [(kq ^ (mr & 7)) * 8];     \
            bf16x8 af1 = *(const bf16x8*)&xs[B][16 + mr][(kq ^ (mr & 7)) * 8];     \
            acc0 = __builtin_amdgcn_mfma_f32_16x16x32_bf16(af0, bfw, acc0, 0, 0, 0); \
            acc1 = __builtin_amdgcn_mfma_f32_16x16x32_bf16(af1, bfw, acc1, 0, 0, 0); \
        }                                                                          \
    }

    // 16 pair-iterations = 32 K-tiles of 128.
    for (int t2 = 0; t2 < 16; ++t2) {
        const int t   = 2 * t2;
        const int tp2 = (t + 2 <= 31) ? (t + 2) : 31;   // uniform clamp
        const int tp3 = (t + 3 <= 31) ? (t + 3) : 31;

        // refill e with tile t+2 (in flight across compute+barrier)
        eA0 = *(const float4*)(xsrc + tp2 * 128);
        eA1 = *(const float4*)(xsrc + tp2 * 128 + 4);
        eB0 = *(const float4*)(xsrc + tp2 * 128 + 64);
        eB1 = *(const float4*)(xsrc + tp2 * 128 + 68);
        COMPUTE(0, t)
        *(bf16x8*)d1a = cvt8(oA0, oA1);        // tile t+1 -> buf1
        *(bf16x8*)d1b = cvt8(oB0, oB1);
        __syncthreads();

        // refill o with tile t+3
        oA0 = *(const float4*)(xsrc + tp3 * 128);
        oA1 = *(const float4*)(xsrc + tp3 * 128 + 4);
        oB0 = *(const float4*)(xsrc + tp3 * 128 + 64);
        oB1 = *(const float4*)(xsrc + tp3 * 128 + 68);
        COMPUTE(1, t + 1)
        *(bf16x8*)d0a = cvt8(eA0, eA1);        // tile t+2 -> buf0
        *(bf16x8*)d0b = cvt8(eB0, eB1);
        __syncthreads();
    }
#undef COMPUTE

    // D layout (R13-proven): m = m0 + mf*16 + kg*4+q, r = rcol
    const int rb = w * 2 + (mr >> 3), j = mr & 7;
    #pragma unroll
    for (int q = 0; q < 4; ++q) {
        inter2[i2_idx(blockIdx.x * 2 + 0, rb, kg * 4 + q, j)] = (__bf16)acc0[q];
        inter2[i2_idx(blockIdx.x * 2 + 1, rb, kg * 4 + q, j)] = (__bf16)acc1[q];
    }
}

// ---------------------------------------------------------------------------
// k_by: out = base + s * (inter @ B).  (R8/R11/R13 verbatim, ~6.5 TB/s)
// ---------------------------------------------------------------------------
__global__ __launch_bounds__(256) void k_by(
    const __bf16* __restrict__ inter2, const float* __restrict__ base,
    const int* __restrict__ idx, const __bf16* __restrict__ Bp,
    const float* __restrict__ scal, float* __restrict__ out)
{
    const int o0 = blockIdx.x * 64;
    const int m0 = blockIdx.y * 64;
    const int a  = idx[m0 / TSEQ];
    const float s = scal[a];
    const __bf16* __restrict__ Ba = Bp + (size_t)a * RR * DOUT;
    const int lane = threadIdx.x & 63;
    const int w    = threadIdx.x >> 6;
    const int mr   = lane & 15, kg = lane >> 4;
    const int oc   = o0 + w * 16 + mr;

    f32x4 z = {0.f, 0.f, 0.f, 0.f};
    f32x4 acc[4] = {z, z, z, z};

    #pragma unroll
    for (int ksub = 0; ksub < 2; ++ksub) {
        const int rb = ksub * 4 + kg;
        bf16x8 bfA = *(const bf16x8*)&Ba[((size_t)rb * DOUT + oc) * 8];
        #pragma unroll
        for (int mt = 0; mt < 4; ++mt) {
            bf16x8 afB = *(const bf16x8*)&inter2[i2_idx(m0 / 16 + mt, rb, mr, 0)];
            acc[mt] = __builtin_amdgcn_mfma_f32_16x16x32_bf16(bfA, afB, acc[mt], 0, 0, 0);
        }
    }

    #pragma unroll
    for (int mt = 0; mt < 4; ++mt) {
        size_t off = (size_t)(m0 + mt * 16 + mr) * DOUT + o0 + w * 16 + kg * 4;
        float4 bv = *(const float4*)&base[off];
        float4 o;
        o.x = bv.x + s * acc[mt][0];
        o.y = bv.y + s * acc[mt][1];
        o.z = bv.z + s * acc[mt][2];
        o.w = bv.w + s * acc[mt][3];
        *(float4*)&out[off] = o;
    }
}

// ---------------------------------------------------------------------------
// Fallback kernels (R6 verbatim, 2 MB ws) if ws_size < 10 MB.
// ---------------------------------------------------------------------------
__global__ __launch_bounds__(256) void k_xa_fb(
    const float* __restrict__ x, const int* __restrict__ idx,
    const float* __restrict__ A, __bf16* __restrict__ inter)
{
    const int m0   = blockIdx.x * 32;
    const int a    = idx[m0 / TSEQ];
    const float* __restrict__ Aa = A + (size_t)a * DIN * RR;
    const int lane = threadIdx.x & 63;
    const int rw   = threadIdx.x >> 6;
    const int mr   = lane & 15, kg = lane >> 4;
    const int rcol = rw * 16 + mr;
    const float* __restrict__ xrow0 = x + (size_t)(m0 + mr) * DIN;
    const float* __restrict__ xrow1 = x + (size_t)(m0 + 16 + mr) * DIN;

    f32x4 acc0 = {0.f, 0.f, 0.f, 0.f};
    f32x4 acc1 = {0.f, 0.f, 0.f, 0.f};

    for (int k0 = 0; k0 < DIN; k0 += 64) {
        #pragma unroll
        for (int ksub = 0; ksub < 2; ++ksub) {
            const int koff = k0 + ksub * 32 + kg * 8;
            float4 u0 = *(const float4*)&xrow0[koff];
            float4 u1 = *(const float4*)&xrow0[koff + 4];
            float4 v0 = *(const float4*)&xrow1[koff];
            float4 v1 = *(const float4*)&xrow1[koff + 4];
            bf16x8 af0 = cvt8(u0, u1);
            bf16x8 af1 = cvt8(v0, v1);
            const float* ap = &Aa[(size_t)koff * RR + rcol];
            bf16x8 bf;
            bf[0] = (__bf16)ap[0 * RR]; bf[1] = (__bf16)ap[1 * RR];
            bf[2] = (__bf16)ap[2 * RR]; bf[3] = (__bf16)ap[3 * RR];
            bf[4] = (__bf16)ap[4 * RR]; bf[5] = (__bf16)ap[5 * RR];
            bf[6] = (__bf16)ap[6 * RR]; bf[7] = (__bf16)ap[7 * RR];
            acc0 = __builtin_amdgcn_mfma_f32_16x16x32_bf16(af0, bf, acc0, 0, 0, 0);
            acc1 = __builtin_amdgcn_mfma_f32_16x16x32_bf16(af1, bf, acc1, 0, 0, 0);
        }
    }
    #pragma unroll
    for (int q = 0; q < 4; ++q) {
        inter[(size_t)(m0 + kg * 4 + q) * RR + rcol]      = (__bf16)acc0[q];
        inter[(size_t)(m0 + 16 + kg * 4 + q) * RR + rcol] = (__bf16)acc1[q];
    }
}

__global__ __launch_bounds__(256) void k_by_fb(
    const __bf16* __restrict__ inter, const float* __restrict__ base,
    const int* __restrict__ idx, const float* __restrict__ Bw,
    const float* __restrict__ scal, float* __restrict__ out)
{
    const int o0 = blockIdx.x * 64;
    const int m0 = blockIdx.y * 64;
    const int a  = idx[m0 / TSEQ];
    const float s = scal[a];
    const float* __restrict__ Ba = Bw + (size_t)a * RR * DOUT;
    const int lane = threadIdx.x & 63;
    const int w    = threadIdx.x >> 6;
    const int mr   = lane & 15, kg = lane >> 4;
    const int oc   = o0 + w * 16 + mr;

    f32x4 z = {0.f, 0.f, 0.f, 0.f};
    f32x4 acc[4] = {z, z, z, z};

    #pragma unroll
    for (int ksub = 0; ksub < 2; ++ksub) {
        const int kb = ksub * 32 + kg * 8;
        const float* bp = &Ba[(size_t)kb * DOUT + oc];
        bf16x8 bf;
        bf[0] = (__bf16)bp[0 * DOUT]; bf[1] = (__bf16)bp[1 * DOUT];
        bf[2] = (__bf16)bp[2 * DOUT]; bf[3] = (__bf16)bp[3 * DOUT];
        bf[4] = (__bf16)bp[4 * DOUT]; bf[5] = (__bf16)bp[5 * DOUT];
        bf[6] = (__bf16)bp[6 * DOUT]; bf[7] = (__bf16)bp[7 * DOUT];
        #pragma unroll
        for (int mt = 0; mt < 4; ++mt) {
            bf16x8 af = *(const bf16x8*)&inter[(size_t)(m0 + mt * 16 + mr) * RR + kb];
            acc[mt] = __builtin_amdgcn_mfma_f32_16x16x32_bf16(af, bf, acc[mt], 0, 0, 0);
        }
    }
    #pragma unroll
    for (int mt = 0; mt < 4; ++mt) {
        #pragma unroll
        for (int q = 0; q < 4; ++q) {
            size_t off = (size_t)(m0 + mt * 16 + kg * 4 + q) * DOUT + oc;
            out[off] = base[off] + s * acc[mt][q];
        }
    }
}

// ---------------------------------------------------------------------------
extern "C" void kernel_launch(void* const* d_in, const int* in_sizes, int n_in,
                              void* d_out, int out_size, void* d_ws, size_t ws_size,
                              hipStream_t stream)
{
    const float* x    = (const float*)d_in[0];
    const float* base = (const float*)d_in[1];
    const int*   idx  = (const int*)  d_in[2];
    const float* A    = (const float*)d_in[3];
    const float* Bw   = (const float*)d_in[4];
    const float* scal = (const float*)d_in[5];
    float* out = (float*)d_out;

    const size_t INTER_B = (size_t)BT * RR * 2;              // 2 MB
    const size_t AT_B    = (size_t)NADP * RR * DIN * 2;      // 4 MB
    const size_t BT_B    = (size_t)NADP * DOUT * RR * 2;     // 4 MB

    if (ws_size >= INTER_B + AT_B + BT_B) {                  // 10 MB path
        __bf16* inter2 = (__bf16*)d_ws;
        __bf16* At2    = (__bf16*)((char*)d_ws + INTER_B);
        __bf16* Bp     = (__bf16*)((char*)d_ws + INTER_B + AT_B);
        k_prep_a<<<dim3(1024), 256, 0, stream>>>(A, At2);
        k_prep_b<<<dim3(1024), 256, 0, stream>>>(Bw, Bp);
        k_xa<<<dim3(BT / 32),            256, 0, stream>>>(x, idx, At2, inter2);
        k_by<<<dim3(DOUT / 64, BT / 64), 256, 0, stream>>>(inter2, base, idx, Bp, scal, out);
    } else {                                                 // 2 MB fallback
        __bf16* inter = (__bf16*)d_ws;
        k_xa_fb<<<dim3(BT / 32),            256, 0, stream>>>(x, idx, A, inter);
        k_by_fb<<<dim3(DOUT / 64, BT / 64), 256, 0, stream>>>(inter, base, idx, Bw, scal, out);
    }
}

// Round 21
// 199.061 us; speedup vs baseline: 1.0552x; 1.0552x over previous
//
#include <hip/hip_runtime.h>
#include <hip/hip_bf16.h>
#include <cstdint>
#include <cstddef>

#define BT    16384   // B*T
#define DIN   4096
#define DOUT  4096
#define RR    64
#define TSEQ  2048
#define NADP  8

typedef float  f32x4  __attribute__((ext_vector_type(4)));
typedef __bf16 bf16x8 __attribute__((ext_vector_type(8)));

static __device__ __forceinline__ unsigned short bf16_bits(float f) {
    return __builtin_bit_cast(unsigned short, (__bf16)f);
}

// inter2 swizzled layout: [mblk(1024)][rb(8)][mrow(16)][j(8)]
static __device__ __forceinline__ size_t i2_idx(int mblk, int rb, int mrow, int j) {
    return ((((size_t)mblk * 8 + rb) * 16 + mrow) * 8 + j);
}

static __device__ __forceinline__ bf16x8 cvt8(float4 a, float4 b) {
    bf16x8 v;
    v[0] = (__bf16)a.x; v[1] = (__bf16)a.y; v[2] = (__bf16)a.z; v[3] = (__bf16)a.w;
    v[4] = (__bf16)b.x; v[5] = (__bf16)b.y; v[6] = (__bf16)b.z; v[7] = (__bf16)b.w;
    return v;
}

// ---------------------------------------------------------------------------
// k_prep_a: At2[a][kb][r][j] = bf16(A[a][kb*8+j][r]).
// ---------------------------------------------------------------------------
__global__ __launch_bounds__(256) void k_prep_a(
    const float* __restrict__ A, __bf16* __restrict__ At2)
{
    const int gtid = blockIdx.x * 256 + threadIdx.x;
    const int r  = gtid & 63;
    const int kb = (gtid >> 6) & (DIN / 8 - 1);
    const int a  = gtid >> 15;
    const float* __restrict__ src = A + (size_t)a * DIN * RR + (size_t)kb * 8 * RR + r;
    unsigned int u[4];
    #pragma unroll
    for (int p = 0; p < 4; ++p) {
        unsigned int lo = bf16_bits(src[(2 * p + 0) * RR]);
        unsigned int hi = bf16_bits(src[(2 * p + 1) * RR]);
        u[p] = lo | (hi << 16);
    }
    *(uint4*)&At2[(size_t)gtid * 8] = make_uint4(u[0], u[1], u[2], u[3]);
}

// ---------------------------------------------------------------------------
// k_prep_b: Bp[a][rb][o][j] = bf16(B[a][rb*8+j][o]).
// ---------------------------------------------------------------------------
__global__ __launch_bounds__(256) void k_prep_b(
    const float* __restrict__ Bw, __bf16* __restrict__ Bp)
{
    const int gtid = blockIdx.x * 256 + threadIdx.x;
    const int o  = gtid & (DOUT - 1);
    const int rb = (gtid >> 12) & 7;
    const int a  = gtid >> 15;
    const float* __restrict__ src = Bw + (size_t)a * RR * DOUT + (size_t)rb * 8 * DOUT + o;
    unsigned int u[4];
    #pragma unroll
    for (int p = 0; p < 4; ++p) {
        unsigned int lo = bf16_bits(src[(2 * p + 0) * DOUT]);
        unsigned int hi = bf16_bits(src[(2 * p + 1) * DOUT]);
        u[p] = lo | (hi << 16);
    }
    *(uint4*)&Bp[(size_t)gtid * 8] = make_uint4(u[0], u[1], u[2], u[3]);
}

// ---------------------------------------------------------------------------
// k_xa: inter2 <- bf16( x @ A[a] ).
// 512 blocks (32 m-rows) x 4 waves, 2 blocks/CU. Double-buffered bf16 x-tile
// in LDS [2][32][64] (8 KB), reg-staged 2 tiles ahead, XOR-swizzled
// (k-octet ^= row&7, applied on BOTH write and read -> conflict-free reads).
// Wave w: all 32 rows x r-tile [w*16,+16): 2 MFMA chains; A-frag loaded once
// per K-step from At2 (L2-hot, 16B coalesced). One barrier per K-tile.
// Best measured configuration (R13 bench: total 199.3 us).
// ---------------------------------------------------------------------------
__global__ __launch_bounds__(256, 2) void k_xa(
    const float* __restrict__ x, const int* __restrict__ idx,
    const __bf16* __restrict__ At2, __bf16* __restrict__ inter2)
{
    __shared__ __bf16 xs[2][32][64];

    const int tid  = threadIdx.x;
    const int m0   = blockIdx.x * 32;
    const int a    = idx[m0 / TSEQ];
    const int w    = tid >> 6, lane = tid & 63;
    const int mr   = lane & 15, kg = lane >> 4;

    // staging geometry: thread -> (row, k-octet slot); source k pre-swizzled
    const int srow = tid >> 3;                 // 0..31
    const int sj   = tid & 7;                  // 0..7  (dest LDS octet)
    const int sk8  = sj ^ (srow & 7);          // swizzled source k-octet
    const float* __restrict__ xsrc = x + (size_t)(m0 + srow) * DIN + sk8 * 8;
    __bf16* const xdst0 = &xs[0][srow][sj * 8];
    __bf16* const xdst1 = &xs[1][srow][sj * 8];

    const __bf16* __restrict__ Aw = At2 + (size_t)a * RR * DIN;
    const int rcol = w * 16 + mr;              // this wave-lane's r column

    f32x4 z = {0.f, 0.f, 0.f, 0.f};
    f32x4 acc0 = z, acc1 = z;                  // m-frag 0 (rows 0-15), 1 (16-31)

    float4 rbA0, rbA1, rbB0, rbB1;             // named staging regs

    // prologue: issue L(0)->rbA, L(1)->rbB; write tile 0; barrier
    rbA0 = *(const float4*)(xsrc + 0 * 64);
    rbA1 = *(const float4*)(xsrc + 0 * 64 + 4);
    rbB0 = *(const float4*)(xsrc + 1 * 64);
    rbB1 = *(const float4*)(xsrc + 1 * 64 + 4);
    *(bf16x8*)xdst0 = cvt8(rbA0, rbA1);
    __syncthreads();

    // 32 pair-iterations = 64 K-tiles. Even tile t: compute buf0, write rbB
    // (tile t+1) -> buf1, refill rbA with L(t+2). Odd: mirrored.
    for (int t2 = 0; t2 < 32; ++t2) {
        const int t = 2 * t2;
        const int tp2 = (t + 2 <= 63) ? (t + 2) : 63;   // uniform clamp
        const int tp3 = (t + 3 <= 63) ? (t + 3) : 63;

        // ---- even tile t: buf0 ----
        rbA0 = *(const float4*)(xsrc + tp2 * 64);
        rbA1 = *(const float4*)(xsrc + tp2 * 64 + 4);
        #pragma unroll
        for (int kstep = 0; kstep < 2; ++kstep) {
            const int kq = kstep * 4 + kg;                       // 0..7
            bf16x8 bfw = *(const bf16x8*)&Aw[((size_t)(t * 8 + kq) * 64 + rcol) * 8];
            bf16x8 af0 = *(const bf16x8*)&xs[0][mr]     [(kq ^ (mr & 7)) * 8];
            bf16x8 af1 = *(const bf16x8*)&xs[0][16 + mr][(kq ^ (mr & 7)) * 8];
            acc0 = __builtin_amdgcn_mfma_f32_16x16x32_bf16(af0, bfw, acc0, 0, 0, 0);
            acc1 = __builtin_amdgcn_mfma_f32_16x16x32_bf16(af1, bfw, acc1, 0, 0, 0);
        }
        *(bf16x8*)xdst1 = cvt8(rbB0, rbB1);    // tile t+1 -> buf1 (vmcnt hidden)
        __syncthreads();

        // ---- odd tile t+1: buf1 ----
        rbB0 = *(const float4*)(xsrc + tp3 * 64);
        rbB1 = *(const float4*)(xsrc + tp3 * 64 + 4);
        #pragma unroll
        for (int kstep = 0; kstep < 2; ++kstep) {
            const int kq = kstep * 4 + kg;
            bf16x8 bfw = *(const bf16x8*)&Aw[((size_t)((t + 1) * 8 + kq) * 64 + rcol) * 8];
            bf16x8 af0 = *(const bf16x8*)&xs[1][mr]     [(kq ^ (mr & 7)) * 8];
            bf16x8 af1 = *(const bf16x8*)&xs[1][16 + mr][(kq ^ (mr & 7)) * 8];
            acc0 = __builtin_amdgcn_mfma_f32_16x16x32_bf16(af0, bfw, acc0, 0, 0, 0);
            acc1 = __builtin_amdgcn_mfma_f32_16x16x32_bf16(af1, bfw, acc1, 0, 0, 0);
        }
        *(bf16x8*)xdst0 = cvt8(rbA0, rbA1);    // tile t+2 -> buf0
        __syncthreads();
    }

    // D layout: row = kg*4+q (m within 16), col = mr -> rcol.
    // logical m = m0 + mf*16 + kg*4+q ; r = w*16 + mr.
    const int rb = w * 2 + (mr >> 3), j = mr & 7;
    #pragma unroll
    for (int q = 0; q < 4; ++q) {
        inter2[i2_idx(blockIdx.x * 2 + 0, rb, kg * 4 + q, j)] = (__bf16)acc0[q];
        inter2[i2_idx(blockIdx.x * 2 + 1, rb, kg * 4 + q, j)] = (__bf16)acc1[q];
    }
}

// ---------------------------------------------------------------------------
// k_by: out = base + s * (inter @ B).  (operand-swapped, coalesced layouts,
// ~6.5 TB/s — at the HBM ceiling for its 524 MB stream)
// ---------------------------------------------------------------------------
__global__ __launch_bounds__(256) void k_by(
    const __bf16* __restrict__ inter2, const float* __restrict__ base,
    const int* __restrict__ idx, const __bf16* __restrict__ Bp,
    const float* __restrict__ scal, float* __restrict__ out)
{
    const int o0 = blockIdx.x * 64;
    const int m0 = blockIdx.y * 64;
    const int a  = idx[m0 / TSEQ];
    const float s = scal[a];
    const __bf16* __restrict__ Ba = Bp + (size_t)a * RR * DOUT;
    const int lane = threadIdx.x & 63;
    const int w    = threadIdx.x >> 6;
    const int mr   = lane & 15, kg = lane >> 4;
    const int oc   = o0 + w * 16 + mr;

    f32x4 z = {0.f, 0.f, 0.f, 0.f};
    f32x4 acc[4] = {z, z, z, z};

    #pragma unroll
    for (int ksub = 0; ksub < 2; ++ksub) {
        const int rb = ksub * 4 + kg;
        bf16x8 bfA = *(const bf16x8*)&Ba[((size_t)rb * DOUT + oc) * 8];
        #pragma unroll
        for (int mt = 0; mt < 4; ++mt) {
            bf16x8 afB = *(const bf16x8*)&inter2[i2_idx(m0 / 16 + mt, rb, mr, 0)];
            acc[mt] = __builtin_amdgcn_mfma_f32_16x16x32_bf16(bfA, afB, acc[mt], 0, 0, 0);
        }
    }

    #pragma unroll
    for (int mt = 0; mt < 4; ++mt) {
        size_t off = (size_t)(m0 + mt * 16 + mr) * DOUT + o0 + w * 16 + kg * 4;
        float4 bv = *(const float4*)&base[off];
        float4 o;
        o.x = bv.x + s * acc[mt][0];
        o.y = bv.y + s * acc[mt][1];
        o.z = bv.z + s * acc[mt][2];
        o.w = bv.w + s * acc[mt][3];
        *(float4*)&out[off] = o;
    }
}

// ---------------------------------------------------------------------------
// Fallback kernels (R6 lineage, 2 MB ws) if ws_size < 10 MB.
// ---------------------------------------------------------------------------
__global__ __launch_bounds__(256) void k_xa_fb(
    const float* __restrict__ x, const int* __restrict__ idx,
    const float* __restrict__ A, __bf16* __restrict__ inter)
{
    const int m0   = blockIdx.x * 32;
    const int a    = idx[m0 / TSEQ];
    const float* __restrict__ Aa = A + (size_t)a * DIN * RR;
    const int lane = threadIdx.x & 63;
    const int rw   = threadIdx.x >> 6;
    const int mr   = lane & 15, kg = lane >> 4;
    const int rcol = rw * 16 + mr;
    const float* __restrict__ xrow0 = x + (size_t)(m0 + mr) * DIN;
    const float* __restrict__ xrow1 = x + (size_t)(m0 + 16 + mr) * DIN;

    f32x4 acc0 = {0.f, 0.f, 0.f, 0.f};
    f32x4 acc1 = {0.f, 0.f, 0.f, 0.f};

    for (int k0 = 0; k0 < DIN; k0 += 64) {
        #pragma unroll
        for (int ksub = 0; ksub < 2; ++ksub) {
            const int koff = k0 + ksub * 32 + kg * 8;
            float4 u0 = *(const float4*)&xrow0[koff];
            float4 u1 = *(const float4*)&xrow0[koff + 4];
            float4 v0 = *(const float4*)&xrow1[koff];
            float4 v1 = *(const float4*)&xrow1[koff + 4];
            bf16x8 af0 = cvt8(u0, u1);
            bf16x8 af1 = cvt8(v0, v1);
            const float* ap = &Aa[(size_t)koff * RR + rcol];
            bf16x8 bf;
            bf[0] = (__bf16)ap[0 * RR]; bf[1] = (__bf16)ap[1 * RR];
            bf[2] = (__bf16)ap[2 * RR]; bf[3] = (__bf16)ap[3 * RR];
            bf[4] = (__bf16)ap[4 * RR]; bf[5] = (__bf16)ap[5 * RR];
            bf[6] = (__bf16)ap[6 * RR]; bf[7] = (__bf16)ap[7 * RR];
            acc0 = __builtin_amdgcn_mfma_f32_16x16x32_bf16(af0, bf, acc0, 0, 0, 0);
            acc1 = __builtin_amdgcn_mfma_f32_16x16x32_bf16(af1, bf, acc1, 0, 0, 0);
        }
    }
    #pragma unroll
    for (int q = 0; q < 4; ++q) {
        inter[(size_t)(m0 + kg * 4 + q) * RR + rcol]      = (__bf16)acc0[q];
        inter[(size_t)(m0 + 16 + kg * 4 + q) * RR + rcol] = (__bf16)acc1[q];
    }
}

__global__ __launch_bounds__(256) void k_by_fb(
    const __bf16* __restrict__ inter, const float* __restrict__ base,
    const int* __restrict__ idx, const float* __restrict__ Bw,
    const float* __restrict__ scal, float* __restrict__ out)
{
    const int o0 = blockIdx.x * 64;
    const int m0 = blockIdx.y * 64;
    const int a  = idx[m0 / TSEQ];
    const float s = scal[a];
    const float* __restrict__ Ba = Bw + (size_t)a * RR * DOUT;
    const int lane = threadIdx.x & 63;
    const int w    = threadIdx.x >> 6;
    const int mr   = lane & 15, kg = lane >> 4;
    const int oc   = o0 + w * 16 + mr;

    f32x4 z = {0.f, 0.f, 0.f, 0.f};
    f32x4 acc[4] = {z, z, z, z};

    #pragma unroll
    for (int ksub = 0; ksub < 2; ++ksub) {
        const int kb = ksub * 32 + kg * 8;
        const float* bp = &Ba[(size_t)kb * DOUT + oc];
        bf16x8 bf;
        bf[0] = (__bf16)bp[0 * DOUT]; bf[1] = (__bf16)bp[1 * DOUT];
        bf[2] = (__bf16)bp[2 * DOUT]; bf[3] = (__bf16)bp[3 * DOUT];
        bf[4] = (__bf16)bp[4 * DOUT]; bf[5] = (__bf16)bp[5 * DOUT];
        bf[6] = (__bf16)bp[6 * DOUT]; bf[7] = (__bf16)bp[7 * DOUT];
        #pragma unroll
        for (int mt = 0; mt < 4; ++mt) {
            bf16x8 af = *(const bf16x8*)&inter[(size_t)(m0 + mt * 16 + mr) * RR + kb];
            acc[mt] = __builtin_amdgcn_mfma_f32_16x16x32_bf16(af, bf, acc[mt], 0, 0, 0);
        }
    }
    #pragma unroll
    for (int mt = 0; mt < 4; ++mt) {
        #pragma unroll
        for (int q = 0; q < 4; ++q) {
            size_t off = (size_t)(m0 + mt * 16 + kg * 4 + q) * DOUT + oc;
            out[off] = base[off] + s * acc[mt][q];
        }
    }
}

// ---------------------------------------------------------------------------
extern "C" void kernel_launch(void* const* d_in, const int* in_sizes, int n_in,
                              void* d_out, int out_size, void* d_ws, size_t ws_size,
                              hipStream_t stream)
{
    const float* x    = (const float*)d_in[0];
    const float* base = (const float*)d_in[1];
    const int*   idx  = (const int*)  d_in[2];
    const float* A    = (const float*)d_in[3];
    const float* Bw   = (const float*)d_in[4];
    const float* scal = (const float*)d_in[5];
    float* out = (float*)d_out;

    const size_t INTER_B = (size_t)BT * RR * 2;              // 2 MB
    const size_t AT_B    = (size_t)NADP * RR * DIN * 2;      // 4 MB
    const size_t BT_B    = (size_t)NADP * DOUT * RR * 2;     // 4 MB

    if (ws_size >= INTER_B + AT_B + BT_B) {                  // 10 MB path
        __bf16* inter2 = (__bf16*)d_ws;
        __bf16* At2    = (__bf16*)((char*)d_ws + INTER_B);
        __bf16* Bp     = (__bf16*)((char*)d_ws + INTER_B + AT_B);
        k_prep_a<<<dim3(1024), 256, 0, stream>>>(A, At2);
        k_prep_b<<<dim3(1024), 256, 0, stream>>>(Bw, Bp);
        k_xa<<<dim3(BT / 32),            256, 0, stream>>>(x, idx, At2, inter2);
        k_by<<<dim3(DOUT / 64, BT / 64), 256, 0, stream>>>(inter2, base, idx, Bp, scal, out);
    } else {                                                 // 2 MB fallback
        __bf16* inter = (__bf16*)d_ws;
        k_xa_fb<<<dim3(BT / 32),            256, 0, stream>>>(x, idx, A, inter);
        k_by_fb<<<dim3(DOUT / 64, BT / 64), 256, 0, stream>>>(inter, base, idx, Bw, scal, out);
    }
}